// Round 9
// baseline (224.119 us; speedup 1.0000x reference)
//
#include <hip/hip_runtime.h>
#include <hip/hip_fp16.h>

// Memory_Attention: r = softmax_L(memory @ qs^T) @ qs ; out = (r, memory)
// B=8 L=4096 D=1024 M=512, fp32 in/out.
//
// Round 9: QK fused-cvt was 103us (vs 40 for gload_lds form) -> revert QK's
// B-side to qs16 via global_load_lds; qs16 produced by a PURE streaming cvt
// (no LDS/transpose; that was the slow part of old prep). PV keeps its fused
// in-LDS fp32 transpose staging (measured good, ~44us).
// Pipeline: prep_mem16 + prep_qs16 -> gemm_qk -> softmax -> gemm_pv(split-K x4)
//           -> combine_scale.  rp overlays S.

#define B_ 8
#define L_ 4096
#define D_ 1024
#define M_ 512

typedef _Float16 halfT;
typedef _Float16 half8 __attribute__((ext_vector_type(8)));
typedef _Float16 half4_t __attribute__((ext_vector_type(4)));
typedef float f32x4 __attribute__((ext_vector_type(4)));

// ---- ws layout (bytes) ----
#define OFF_MEM16 0ull
#define SZ_MEM16  (512ull*1024*2)             //  1,048,576
#define OFF_QS16  (OFF_MEM16 + SZ_MEM16)
#define SZ_QS16   (8ull*4096*1024*2)          // 67,108,864
#define OFF_S     (OFF_QS16 + SZ_QS16)
#define SZ_S      (8ull*512*4096*4)           // 67,108,864
#define OFF_P16   (OFF_S + SZ_S)
#define SZ_P16    (8ull*512*4096*2)           // 33,554,432
#define OFF_INVL  (OFF_P16 + SZ_P16)
#define SZ_INVL   (8ull*512*4)
#define WS_NEED   (OFF_INVL + SZ_INVL)        // ~168.8 MB (ws known >= 202 MB)
#define OFF_RP    OFF_S                       // overlay: S dead after softmax

#define SWZ(n) ((((n)&7) ^ (((n)>>5)&7)))

__device__ __forceinline__ void gload_lds16(const halfT* g, halfT* l) {
  __builtin_amdgcn_global_load_lds(
      (const __attribute__((address_space(1))) unsigned int*)(const void*)g,
      (__attribute__((address_space(3))) unsigned int*)l, 16, 0, 0);
}

// ---------------- prep: pure streaming fp32 -> fp16 ----------------
__global__ void prep_mem16(const float* __restrict__ mem, halfT* __restrict__ mem16) {
  int i = blockIdx.x*256 + threadIdx.x;   // 2048*256 = 524288 exact
  mem16[i] = (halfT)mem[i];
}

// 33,554,432 elems; 2048 blk x 256 thr x 8 iter x 8 elems (32B read / 16B write).
__global__ __launch_bounds__(256)
void prep_qs16(const float* __restrict__ qs, halfT* __restrict__ q16) {
  size_t base = (size_t)blockIdx.x*256 + threadIdx.x;
  #pragma unroll
  for (int it = 0; it < 8; ++it) {
    size_t e = (base + (size_t)it*524288)*8;
    f32x4 x0 = *(const f32x4*)&qs[e];
    f32x4 x1 = *(const f32x4*)&qs[e + 4];
    half8 h;
    #pragma unroll
    for (int j = 0; j < 4; ++j) { h[j] = (halfT)x0[j]; h[4+j] = (halfT)x1[j]; }
    *(half8*)&q16[e] = h;
  }
}

// ---------------- gemm_qk: S[b][512][4096] = mem16 @ qs16^T ----------------
// 256^2 tile, BK=64, 8 waves, 2-phase dbuf, both operands via global_load_lds
// (round-7 gemm_bt form, specialized). Per b: MT=2, NT=16. Grid 256.
__global__ __launch_bounds__(512, 2)
void gemm_qk(const halfT* __restrict__ mem16, const halfT* __restrict__ qs16,
             float* __restrict__ S)
{
  __shared__ __attribute__((aligned(16))) halfT At[2][256*64];   // 64 KB
  __shared__ __attribute__((aligned(16))) halfT Bt[2][256*64];   // 64 KB

  int bid = blockIdx.x;                      // 256
  int swz = (bid & 7)*32 + (bid >> 3);       // XCD-contiguous
  int b   = swz >> 5;                        // one b per XCD
  int rem = swz & 31;
  int nt  = rem >> 1;
  int mt  = rem & 1;

  int tid = threadIdx.x;
  int w = tid >> 6, lane = tid & 63, lg = lane >> 4, li = lane & 15;
  int wm = w >> 2, wn = w & 3;
  int rA = tid >> 3;               // staging row base (0..63), +64 per j
  int cA = (tid & 7)*8;            // staging col (halfs)

  const halfT* Ab = mem16 + (size_t)mt*256*1024;
  const halfT* Bb = qs16 + ((size_t)b*L_ + nt*256)*D_;

  f32x4 acc[8][4];
  #pragma unroll
  for (int i=0;i<8;++i)
    #pragma unroll
    for (int j=0;j<4;++j) acc[i][j] = (f32x4){0.f,0.f,0.f,0.f};

#define STAGE_QK(nb_, kt_)                                                     \
  do {                                                                         \
    const halfT* a0 = Ab + (size_t)(kt_)*64 + cA;                              \
    const halfT* b0 = Bb + (size_t)(kt_)*64 + cA;                              \
    _Pragma("unroll")                                                          \
    for (int j = 0; j < 4; ++j) {                                              \
      int r = rA + j*64;                                                       \
      gload_lds16(a0 + (size_t)r*1024, &At[nb_][(tid + j*512)*8]);             \
      gload_lds16(b0 + (size_t)r*1024, &Bt[nb_][(tid + j*512)*8]);             \
    }                                                                          \
  } while (0)

  STAGE_QK(0, 0);
  __syncthreads();                           // prologue drain

  int nb = 0;
  for (int kt = 0; kt < 16; ++kt) {
    if (kt + 1 < 16) STAGE_QK(nb ^ 1, kt + 1);
    #pragma unroll
    for (int ksub = 0; ksub < 2; ++ksub) {
      half8 Af[8], Bf[4];
      #pragma unroll
      for (int mf = 0; mf < 8; ++mf)
        Af[mf] = *(const half8*)&At[nb][(wm*128 + mf*16 + li)*64 + ksub*32 + lg*8];
      #pragma unroll
      for (int nf = 0; nf < 4; ++nf)
        Bf[nf] = *(const half8*)&Bt[nb][(wn*64 + nf*16 + li)*64 + ksub*32 + lg*8];
      #pragma unroll
      for (int mf = 0; mf < 8; ++mf)
        #pragma unroll
        for (int nf = 0; nf < 4; ++nf)
          acc[mf][nf] = __builtin_amdgcn_mfma_f32_16x16x32_f16(Af[mf], Bf[nf], acc[mf][nf], 0,0,0);
    }
    __syncthreads();                         // drains prefetch + lds reads
    nb ^= 1;
  }
#undef STAGE_QK

  float* Cb = S + (size_t)b*M_*L_;
  int colbase = nt*256 + wn*64;
  #pragma unroll
  for (int mf = 0; mf < 8; ++mf) {
    #pragma unroll
    for (int r = 0; r < 4; ++r) {
      int row = mt*256 + wm*128 + mf*16 + lg*4 + r;
      #pragma unroll
      for (int nf = 0; nf < 4; ++nf)
        Cb[(size_t)row*L_ + colbase + nf*16 + li] = acc[mf][nf][r];
    }
  }
}

// ---------------- gemm_pv: rp[ks][b][512][1024] = P16 @ qs (K-chunk ks) ----------------
// Unchanged from round 8 (measured fast). A=P16 gload_lds; B=qs fp32 reg-staged
// in-LDS transpose (32 scalar swizzled ds_write_u16) into [n][64k] XOR layout.
__global__ __launch_bounds__(512, 2)
void gemm_pv(const halfT* __restrict__ P16, const float* __restrict__ qs,
             float* __restrict__ rp)
{
  __shared__ __attribute__((aligned(16))) halfT At[2][256*64];   // 64 KB
  __shared__ __attribute__((aligned(16))) halfT Bt[2][256*64];   // 64 KB

  int bid = blockIdx.x;                      // 256
  int swz = (bid & 7)*32 + (bid >> 3);
  int ks  = swz >> 6;                        // 0..3
  int rem = swz & 63;
  int b   = rem >> 3;
  int nt  = (rem >> 1) & 3;
  int mt  = rem & 1;

  int tid = threadIdx.x;
  int w = tid >> 6, lane = tid & 63, lg = lane >> 4, li = lane & 15;
  int wm = w >> 2, wn = w & 3;

  const halfT* Ab = P16 + (size_t)b*M_*L_ + (size_t)mt*256*L_ + ks*1024;
  const float* Bb = qs + ((size_t)b*L_ + ks*1024)*D_ + nt*256;
  int krow = tid >> 3;                       // 0..63
  int seg  = tid & 7;

  f32x4 acc[8][4];
  #pragma unroll
  for (int i=0;i<8;++i)
    #pragma unroll
    for (int j=0;j<4;++j) acc[i][j] = (f32x4){0.f,0.f,0.f,0.f};

  f32x4 bx[8];

#define GLOADB_PV(kt_)                                                         \
  do {                                                                         \
    const float* src = Bb + (size_t)((kt_)*64 + krow)*D_ + seg*32;             \
    _Pragma("unroll")                                                          \
    for (int j = 0; j < 8; ++j) bx[j] = *(const f32x4*)(src + j*4);            \
  } while (0)

#define STAGEA_PV(nb_, kt_)                                                    \
  do {                                                                         \
    const halfT* a0 = Ab + (size_t)(kt_)*64 + (tid & 7)*8;                     \
    _Pragma("unroll")                                                          \
    for (int j = 0; j < 4; ++j)                                                \
      gload_lds16(a0 + (size_t)((tid >> 3) + j*64)*L_, &At[nb_][(tid + j*512)*8]); \
  } while (0)

#define CVTWRITE_PV(nb_)                                                       \
  do {                                                                         \
    _Pragma("unroll")                                                          \
    for (int i = 0; i < 32; ++i) {                                             \
      int n_ = seg*32 + i;                                                     \
      Bt[nb_][n_*64 + ((((krow >> 3) ^ SWZ(n_)) << 3)) + (krow & 7)] =         \
          (halfT)bx[i >> 2][i & 3];                                            \
    }                                                                          \
  } while (0)

  GLOADB_PV(0);
  STAGEA_PV(0, 0);
  CVTWRITE_PV(0);
  __syncthreads();

  int nb = 0;
  for (int kt = 0; kt < 16; ++kt) {
    if (kt + 1 < 16) { GLOADB_PV(kt + 1); STAGEA_PV(nb ^ 1, kt + 1); }
    #pragma unroll
    for (int ksub = 0; ksub < 2; ++ksub) {
      half8 Af[8], Bf[4];
      #pragma unroll
      for (int mf = 0; mf < 8; ++mf)
        Af[mf] = *(const half8*)&At[nb][(wm*128 + mf*16 + li)*64 + ksub*32 + lg*8];
      #pragma unroll
      for (int nf = 0; nf < 4; ++nf) {
        int n_ = wn*64 + nf*16 + li;
        Bf[nf] = *(const half8*)&Bt[nb][n_*64 + (((ksub*4 + lg) ^ SWZ(n_)) << 3)];
      }
      #pragma unroll
      for (int mf = 0; mf < 8; ++mf)
        #pragma unroll
        for (int nf = 0; nf < 4; ++nf)
          acc[mf][nf] = __builtin_amdgcn_mfma_f32_16x16x32_f16(Af[mf], Bf[nf], acc[mf][nf], 0,0,0);
    }
    if (kt + 1 < 16) CVTWRITE_PV(nb ^ 1);
    __syncthreads();
    nb ^= 1;
  }
#undef GLOADB_PV
#undef STAGEA_PV
#undef CVTWRITE_PV

  float* Cb = rp + (size_t)ks*((size_t)B_*M_*D_) + (size_t)b*M_*D_;
  int colbase = nt*256 + wn*64;
  #pragma unroll
  for (int mf = 0; mf < 8; ++mf) {
    #pragma unroll
    for (int r = 0; r < 4; ++r) {
      int row = mt*256 + wm*128 + mf*16 + lg*4 + r;
      #pragma unroll
      for (int nf = 0; nf < 4; ++nf)
        Cb[(size_t)row*D_ + colbase + nf*16 + li] = acc[mf][nf][r];
    }
  }
}

// ---------------- row softmax: P16 = exp(S - max), invl = 1/sum ----------------
__global__ __launch_bounds__(256)
void softmax_rows(const float* __restrict__ S, halfT* __restrict__ P,
                  float* __restrict__ invl)
{
  __shared__ float red[4];
  int row = blockIdx.x;                    // 0..4095 = b*512+m
  int tid = threadIdx.x;
  const float* src = S + (size_t)row*L_;
  f32x4 v[4];
  float mx = -3.0e38f;
  #pragma unroll
  for (int i = 0; i < 4; ++i) {
    v[i] = *(const f32x4*)&src[(size_t)(i*256 + tid)*4];
    #pragma unroll
    for (int e = 0; e < 4; ++e) mx = fmaxf(mx, v[i][e]);
  }
  #pragma unroll
  for (int off = 1; off < 64; off <<= 1) mx = fmaxf(mx, __shfl_xor(mx, off));
  int w = tid >> 6;
  if ((tid & 63) == 0) red[w] = mx;
  __syncthreads();
  mx = fmaxf(fmaxf(red[0], red[1]), fmaxf(red[2], red[3]));

  float sum = 0.f;
  halfT* dst = P + (size_t)row*L_;
  #pragma unroll
  for (int i = 0; i < 4; ++i) {
    half4_t h;
    #pragma unroll
    for (int e = 0; e < 4; ++e) {
      float ev = __expf(v[i][e] - mx);
      sum += ev;
      h[e] = (halfT)ev;
    }
    *(half4_t*)&dst[(size_t)(i*256 + tid)*4] = h;
  }
  #pragma unroll
  for (int off = 1; off < 64; off <<= 1) sum += __shfl_xor(sum, off);
  __syncthreads();
  if ((tid & 63) == 0) red[w] = sum;
  __syncthreads();
  if (tid == 0) invl[row] = 1.0f / (red[0] + red[1] + red[2] + red[3]);
}

// ---------------- combine: out = invl * sum_ks rp[ks] ----------------
__global__ __launch_bounds__(256)
void combine_scale(const float* __restrict__ rp, const float* __restrict__ invl,
                   float* __restrict__ out)
{
  int bm = blockIdx.x;                     // 0..4095
  int tid = threadIdx.x;
  size_t off = (size_t)bm*D_ + tid*4;
  f32x4 v = *(const f32x4*)&rp[off];
  #pragma unroll
  for (int s = 1; s < 4; ++s)
    v += *(const f32x4*)&rp[(size_t)s*B_*M_*D_ + off];
  float sc = invl[bm];
  v *= sc;
  *(f32x4*)&out[off] = v;
}

// ---------------- fallback (tiny ws): correct, slow fp32 ----------------
__global__ void fallback_kernel(const float* __restrict__ qs,
                                const float* __restrict__ mem,
                                float* __restrict__ out)
{
  __shared__ float w_lds[4][4096];
  __shared__ float mem_s[4][1024];
  __shared__ float redb[256];
  int blk = blockIdx.x;
  int b = blk >> 7;
  int m0 = (blk & 127)*4;
  int tid = threadIdx.x;

  for (int i = tid; i < 4*1024; i += 256)
    mem_s[i>>10][i&1023] = mem[(size_t)(m0 + (i>>10))*D_ + (i&1023)];
  __syncthreads();

  float mx[4] = {-3e38f,-3e38f,-3e38f,-3e38f};
  for (int l = tid; l < L_; l += 256) {
    const float* qp = qs + ((size_t)b*L_ + l)*D_;
    float dot[4] = {0,0,0,0};
    for (int dd = 0; dd < D_; dd += 4) {
      f32x4 qv = *(const f32x4*)(qp + dd);
      #pragma unroll
      for (int mi=0; mi<4; ++mi)
        dot[mi] += qv[0]*mem_s[mi][dd] + qv[1]*mem_s[mi][dd+1]
                 + qv[2]*mem_s[mi][dd+2] + qv[3]*mem_s[mi][dd+3];
    }
    #pragma unroll
    for (int mi=0; mi<4; ++mi) { w_lds[mi][l] = dot[mi]; mx[mi] = fmaxf(mx[mi], dot[mi]); }
  }
  float Mv[4], Zv[4];
  for (int mi=0; mi<4; ++mi) {
    redb[tid] = mx[mi]; __syncthreads();
    for (int s=128; s>0; s>>=1) { if (tid<s) redb[tid]=fmaxf(redb[tid],redb[tid+s]); __syncthreads(); }
    Mv[mi] = redb[0]; __syncthreads();
  }
  float sm[4] = {0,0,0,0};
  for (int l = tid; l < L_; l += 256)
    #pragma unroll
    for (int mi=0; mi<4; ++mi) {
      float wv = __expf(w_lds[mi][l] - Mv[mi]);
      w_lds[mi][l] = wv; sm[mi] += wv;
    }
  for (int mi=0; mi<4; ++mi) {
    redb[tid] = sm[mi]; __syncthreads();
    for (int s=128; s>0; s>>=1) { if (tid<s) redb[tid]+=redb[tid+s]; __syncthreads(); }
    Zv[mi] = redb[0]; __syncthreads();
  }
  int d0 = tid*4;
  f32x4 a[4];
  #pragma unroll
  for (int mi=0;mi<4;++mi) a[mi] = (f32x4){0,0,0,0};
  for (int l = 0; l < L_; ++l) {
    f32x4 qv = *(const f32x4*)(qs + ((size_t)b*L_ + l)*D_ + d0);
    #pragma unroll
    for (int mi=0; mi<4; ++mi) a[mi] += qv * w_lds[mi][l];
  }
  #pragma unroll
  for (int mi=0; mi<4; ++mi) {
    float invz = 1.f/Zv[mi];
    #pragma unroll
    for (int c=0; c<4; ++c)
      out[((size_t)b*M_ + m0 + mi)*D_ + d0 + c] = a[mi][c]*invz;
  }
}

extern "C" void kernel_launch(void* const* d_in, const int* in_sizes, int n_in,
                              void* d_out, int out_size, void* d_ws, size_t ws_size,
                              hipStream_t stream) {
  const float* qs  = (const float*)d_in[0];
  const float* mem = (const float*)d_in[1];
  float* out = (float*)d_out;

  // tuple output: r [8*512*1024] then memory [512*1024]
  hipMemcpyAsync(out + (size_t)B_*M_*D_, mem, (size_t)M_*D_*sizeof(float),
                 hipMemcpyDeviceToDevice, stream);

  if (ws_size >= (size_t)WS_NEED) {
    char* base = (char*)d_ws;
    halfT* mem16 = (halfT*)(base + OFF_MEM16);
    halfT* qs16  = (halfT*)(base + OFF_QS16);
    float* S     = (float*)(base + OFF_S);
    halfT* P16   = (halfT*)(base + OFF_P16);
    float* invl  = (float*)(base + OFF_INVL);
    float* rp    = (float*)(base + OFF_RP);    // overlays S (dead after softmax)

    prep_mem16<<<2048, 256, 0, stream>>>(mem, mem16);
    prep_qs16<<<2048, 256, 0, stream>>>(qs, qs16);
    gemm_qk<<<256, 512, 0, stream>>>(mem16, qs16, S);
    softmax_rows<<<4096, 256, 0, stream>>>(S, P16, invl);
    gemm_pv<<<256, 512, 0, stream>>>(P16, qs, rp);
    combine_scale<<<4096, 256, 0, stream>>>(rp, invl, out);
  } else {
    fallback_kernel<<<1024, 256, 0, stream>>>(qs, mem, out);
  }
}

// Round 10
// 175.661 us; speedup vs baseline: 1.2759x; 1.2759x over previous
//
#include <hip/hip_runtime.h>
#include <hip/hip_fp16.h>

// Memory_Attention: r = softmax_L(memory @ qs^T) @ qs ; out = (r, memory)
// B=8 L=4096 D=1024 M=512, fp32 in/out.
//
// Round 10: gemm_pv B-side switches qs(fp32) -> qs16(fp16). Round-9 lesson:
// reg-staged fp32-B runs ~1.5 TB/s when HBM-sourced (95us cold vs 51us warm);
// fp16 halves the traffic and qs16 is L3-warm (prep wrote it, only ~101MB of
// S/P16 written since). Staging transpose unchanged (scalar swizzled writes),
// minus the cvt. Everything else = round 9.
// Pipeline: prep_mem16 + prep_qs16 -> gemm_qk -> softmax -> gemm_pv(split-K x4)
//           -> combine_scale.  rp overlays S.

#define B_ 8
#define L_ 4096
#define D_ 1024
#define M_ 512

typedef _Float16 halfT;
typedef _Float16 half8 __attribute__((ext_vector_type(8)));
typedef _Float16 half4_t __attribute__((ext_vector_type(4)));
typedef float f32x4 __attribute__((ext_vector_type(4)));

// ---- ws layout (bytes) ----
#define OFF_MEM16 0ull
#define SZ_MEM16  (512ull*1024*2)             //  1,048,576
#define OFF_QS16  (OFF_MEM16 + SZ_MEM16)
#define SZ_QS16   (8ull*4096*1024*2)          // 67,108,864
#define OFF_S     (OFF_QS16 + SZ_QS16)
#define SZ_S      (8ull*512*4096*4)           // 67,108,864
#define OFF_P16   (OFF_S + SZ_S)
#define SZ_P16    (8ull*512*4096*2)           // 33,554,432
#define OFF_INVL  (OFF_P16 + SZ_P16)
#define SZ_INVL   (8ull*512*4)
#define WS_NEED   (OFF_INVL + SZ_INVL)        // ~168.8 MB (ws known >= 202 MB)
#define OFF_RP    OFF_S                       // overlay: S dead after softmax

#define SWZ(n) ((((n)&7) ^ (((n)>>5)&7)))

__device__ __forceinline__ void gload_lds16(const halfT* g, halfT* l) {
  __builtin_amdgcn_global_load_lds(
      (const __attribute__((address_space(1))) unsigned int*)(const void*)g,
      (__attribute__((address_space(3))) unsigned int*)l, 16, 0, 0);
}

// ---------------- prep: pure streaming fp32 -> fp16 ----------------
__global__ void prep_mem16(const float* __restrict__ mem, halfT* __restrict__ mem16) {
  int i = blockIdx.x*256 + threadIdx.x;   // 2048*256 = 524288 exact
  mem16[i] = (halfT)mem[i];
}

// 33,554,432 elems; 2048 blk x 256 thr x 8 iter x 8 elems (32B read / 16B write).
__global__ __launch_bounds__(256)
void prep_qs16(const float* __restrict__ qs, halfT* __restrict__ q16) {
  size_t base = (size_t)blockIdx.x*256 + threadIdx.x;
  #pragma unroll
  for (int it = 0; it < 8; ++it) {
    size_t e = (base + (size_t)it*524288)*8;
    f32x4 x0 = *(const f32x4*)&qs[e];
    f32x4 x1 = *(const f32x4*)&qs[e + 4];
    half8 h;
    #pragma unroll
    for (int j = 0; j < 4; ++j) { h[j] = (halfT)x0[j]; h[4+j] = (halfT)x1[j]; }
    *(half8*)&q16[e] = h;
  }
}

// ---------------- gemm_qk: S[b][512][4096] = mem16 @ qs16^T ----------------
// 256^2 tile, BK=64, 8 waves, 2-phase dbuf, both operands via global_load_lds.
// Per b: MT=2, NT=16. Grid 256.
__global__ __launch_bounds__(512, 2)
void gemm_qk(const halfT* __restrict__ mem16, const halfT* __restrict__ qs16,
             float* __restrict__ S)
{
  __shared__ __attribute__((aligned(16))) halfT At[2][256*64];   // 64 KB
  __shared__ __attribute__((aligned(16))) halfT Bt[2][256*64];   // 64 KB

  int bid = blockIdx.x;                      // 256
  int swz = (bid & 7)*32 + (bid >> 3);       // XCD-contiguous
  int b   = swz >> 5;                        // one b per XCD
  int rem = swz & 31;
  int nt  = rem >> 1;
  int mt  = rem & 1;

  int tid = threadIdx.x;
  int w = tid >> 6, lane = tid & 63, lg = lane >> 4, li = lane & 15;
  int wm = w >> 2, wn = w & 3;
  int rA = tid >> 3;               // staging row base (0..63), +64 per j
  int cA = (tid & 7)*8;            // staging col (halfs)

  const halfT* Ab = mem16 + (size_t)mt*256*1024;
  const halfT* Bb = qs16 + ((size_t)b*L_ + nt*256)*D_;

  f32x4 acc[8][4];
  #pragma unroll
  for (int i=0;i<8;++i)
    #pragma unroll
    for (int j=0;j<4;++j) acc[i][j] = (f32x4){0.f,0.f,0.f,0.f};

#define STAGE_QK(nb_, kt_)                                                     \
  do {                                                                         \
    const halfT* a0 = Ab + (size_t)(kt_)*64 + cA;                              \
    const halfT* b0 = Bb + (size_t)(kt_)*64 + cA;                              \
    _Pragma("unroll")                                                          \
    for (int j = 0; j < 4; ++j) {                                              \
      int r = rA + j*64;                                                       \
      gload_lds16(a0 + (size_t)r*1024, &At[nb_][(tid + j*512)*8]);             \
      gload_lds16(b0 + (size_t)r*1024, &Bt[nb_][(tid + j*512)*8]);             \
    }                                                                          \
  } while (0)

  STAGE_QK(0, 0);
  __syncthreads();                           // prologue drain

  int nb = 0;
  for (int kt = 0; kt < 16; ++kt) {
    if (kt + 1 < 16) STAGE_QK(nb ^ 1, kt + 1);
    #pragma unroll
    for (int ksub = 0; ksub < 2; ++ksub) {
      half8 Af[8], Bf[4];
      #pragma unroll
      for (int mf = 0; mf < 8; ++mf)
        Af[mf] = *(const half8*)&At[nb][(wm*128 + mf*16 + li)*64 + ksub*32 + lg*8];
      #pragma unroll
      for (int nf = 0; nf < 4; ++nf)
        Bf[nf] = *(const half8*)&Bt[nb][(wn*64 + nf*16 + li)*64 + ksub*32 + lg*8];
      #pragma unroll
      for (int mf = 0; mf < 8; ++mf)
        #pragma unroll
        for (int nf = 0; nf < 4; ++nf)
          acc[mf][nf] = __builtin_amdgcn_mfma_f32_16x16x32_f16(Af[mf], Bf[nf], acc[mf][nf], 0,0,0);
    }
    __syncthreads();                         // drains prefetch + lds reads
    nb ^= 1;
  }
#undef STAGE_QK

  float* Cb = S + (size_t)b*M_*L_;
  int colbase = nt*256 + wn*64;
  #pragma unroll
  for (int mf = 0; mf < 8; ++mf) {
    #pragma unroll
    for (int r = 0; r < 4; ++r) {
      int row = mt*256 + wm*128 + mf*16 + lg*4 + r;
      #pragma unroll
      for (int nf = 0; nf < 4; ++nf)
        Cb[(size_t)row*L_ + colbase + nf*16 + li] = acc[mf][nf][r];
    }
  }
}

// ---------------- gemm_pv: rp[ks][b][512][1024] = P16 @ qs16 (K-chunk ks) ----------------
// A=P16 gload_lds; B=qs16 fp16 reg-staged in-LDS transpose (32 scalar swizzled
// ds_write_u16) into [n][64k] XOR layout. Per (b,ks): MT=2, NT=4. Grid 256.
__global__ __launch_bounds__(512, 2)
void gemm_pv(const halfT* __restrict__ P16, const halfT* __restrict__ qs16,
             float* __restrict__ rp)
{
  __shared__ __attribute__((aligned(16))) halfT At[2][256*64];   // 64 KB
  __shared__ __attribute__((aligned(16))) halfT Bt[2][256*64];   // 64 KB

  int bid = blockIdx.x;                      // 256
  int swz = (bid & 7)*32 + (bid >> 3);
  int ks  = swz >> 6;                        // 0..3
  int rem = swz & 63;
  int b   = rem >> 3;
  int nt  = (rem >> 1) & 3;
  int mt  = rem & 1;

  int tid = threadIdx.x;
  int w = tid >> 6, lane = tid & 63, lg = lane >> 4, li = lane & 15;
  int wm = w >> 2, wn = w & 3;

  const halfT* Ab = P16 + (size_t)b*M_*L_ + (size_t)mt*256*L_ + ks*1024;
  const halfT* Bb = qs16 + ((size_t)b*L_ + ks*1024)*D_ + nt*256;
  int krow = tid >> 3;                       // 0..63
  int seg  = tid & 7;

  f32x4 acc[8][4];
  #pragma unroll
  for (int i=0;i<8;++i)
    #pragma unroll
    for (int j=0;j<4;++j) acc[i][j] = (f32x4){0.f,0.f,0.f,0.f};

  half8 hx[4];

#define GLOADB_PV(kt_)                                                         \
  do {                                                                         \
    const halfT* src = Bb + (size_t)((kt_)*64 + krow)*D_ + seg*32;             \
    _Pragma("unroll")                                                          \
    for (int j = 0; j < 4; ++j) hx[j] = *(const half8*)(src + j*8);            \
  } while (0)

#define STAGEA_PV(nb_, kt_)                                                    \
  do {                                                                         \
    const halfT* a0 = Ab + (size_t)(kt_)*64 + (tid & 7)*8;                     \
    _Pragma("unroll")                                                          \
    for (int j = 0; j < 4; ++j)                                                \
      gload_lds16(a0 + (size_t)((tid >> 3) + j*64)*L_, &At[nb_][(tid + j*512)*8]); \
  } while (0)

#define WRITEB_PV(nb_)                                                         \
  do {                                                                         \
    _Pragma("unroll")                                                          \
    for (int i = 0; i < 32; ++i) {                                             \
      int n_ = seg*32 + i;                                                     \
      Bt[nb_][n_*64 + ((((krow >> 3) ^ SWZ(n_)) << 3)) + (krow & 7)] =         \
          hx[i >> 3][i & 7];                                                   \
    }                                                                          \
  } while (0)

  GLOADB_PV(0);
  STAGEA_PV(0, 0);
  WRITEB_PV(0);
  __syncthreads();

  int nb = 0;
  for (int kt = 0; kt < 16; ++kt) {
    if (kt + 1 < 16) { GLOADB_PV(kt + 1); STAGEA_PV(nb ^ 1, kt + 1); }
    #pragma unroll
    for (int ksub = 0; ksub < 2; ++ksub) {
      half8 Af[8], Bf[4];
      #pragma unroll
      for (int mf = 0; mf < 8; ++mf)
        Af[mf] = *(const half8*)&At[nb][(wm*128 + mf*16 + li)*64 + ksub*32 + lg*8];
      #pragma unroll
      for (int nf = 0; nf < 4; ++nf) {
        int n_ = wn*64 + nf*16 + li;
        Bf[nf] = *(const half8*)&Bt[nb][n_*64 + (((ksub*4 + lg) ^ SWZ(n_)) << 3)];
      }
      #pragma unroll
      for (int mf = 0; mf < 8; ++mf)
        #pragma unroll
        for (int nf = 0; nf < 4; ++nf)
          acc[mf][nf] = __builtin_amdgcn_mfma_f32_16x16x32_f16(Af[mf], Bf[nf], acc[mf][nf], 0,0,0);
    }
    if (kt + 1 < 16) WRITEB_PV(nb ^ 1);      // after compute: loads have landed
    __syncthreads();
    nb ^= 1;
  }
#undef GLOADB_PV
#undef STAGEA_PV
#undef WRITEB_PV

  float* Cb = rp + (size_t)ks*((size_t)B_*M_*D_) + (size_t)b*M_*D_;
  int colbase = nt*256 + wn*64;
  #pragma unroll
  for (int mf = 0; mf < 8; ++mf) {
    #pragma unroll
    for (int r = 0; r < 4; ++r) {
      int row = mt*256 + wm*128 + mf*16 + lg*4 + r;
      #pragma unroll
      for (int nf = 0; nf < 4; ++nf)
        Cb[(size_t)row*D_ + colbase + nf*16 + li] = acc[mf][nf][r];
    }
  }
}

// ---------------- row softmax: P16 = exp(S - max), invl = 1/sum ----------------
__global__ __launch_bounds__(256)
void softmax_rows(const float* __restrict__ S, halfT* __restrict__ P,
                  float* __restrict__ invl)
{
  __shared__ float red[4];
  int row = blockIdx.x;                    // 0..4095 = b*512+m
  int tid = threadIdx.x;
  const float* src = S + (size_t)row*L_;
  f32x4 v[4];
  float mx = -3.0e38f;
  #pragma unroll
  for (int i = 0; i < 4; ++i) {
    v[i] = *(const f32x4*)&src[(size_t)(i*256 + tid)*4];
    #pragma unroll
    for (int e = 0; e < 4; ++e) mx = fmaxf(mx, v[i][e]);
  }
  #pragma unroll
  for (int off = 1; off < 64; off <<= 1) mx = fmaxf(mx, __shfl_xor(mx, off));
  int w = tid >> 6;
  if ((tid & 63) == 0) red[w] = mx;
  __syncthreads();
  mx = fmaxf(fmaxf(red[0], red[1]), fmaxf(red[2], red[3]));

  float sum = 0.f;
  halfT* dst = P + (size_t)row*L_;
  #pragma unroll
  for (int i = 0; i < 4; ++i) {
    half4_t h;
    #pragma unroll
    for (int e = 0; e < 4; ++e) {
      float ev = __expf(v[i][e] - mx);
      sum += ev;
      h[e] = (halfT)ev;
    }
    *(half4_t*)&dst[(size_t)(i*256 + tid)*4] = h;
  }
  #pragma unroll
  for (int off = 1; off < 64; off <<= 1) sum += __shfl_xor(sum, off);
  __syncthreads();
  if ((tid & 63) == 0) red[w] = sum;
  __syncthreads();
  if (tid == 0) invl[row] = 1.0f / (red[0] + red[1] + red[2] + red[3]);
}

// ---------------- combine: out = invl * sum_ks rp[ks] ----------------
__global__ __launch_bounds__(256)
void combine_scale(const float* __restrict__ rp, const float* __restrict__ invl,
                   float* __restrict__ out)
{
  int bm = blockIdx.x;                     // 0..4095
  int tid = threadIdx.x;
  size_t off = (size_t)bm*D_ + tid*4;
  f32x4 v = *(const f32x4*)&rp[off];
  #pragma unroll
  for (int s = 1; s < 4; ++s)
    v += *(const f32x4*)&rp[(size_t)s*B_*M_*D_ + off];
  float sc = invl[bm];
  v *= sc;
  *(f32x4*)&out[off] = v;
}

// ---------------- fallback (tiny ws): correct, slow fp32 ----------------
__global__ void fallback_kernel(const float* __restrict__ qs,
                                const float* __restrict__ mem,
                                float* __restrict__ out)
{
  __shared__ float w_lds[4][4096];
  __shared__ float mem_s[4][1024];
  __shared__ float redb[256];
  int blk = blockIdx.x;
  int b = blk >> 7;
  int m0 = (blk & 127)*4;
  int tid = threadIdx.x;

  for (int i = tid; i < 4*1024; i += 256)
    mem_s[i>>10][i&1023] = mem[(size_t)(m0 + (i>>10))*D_ + (i&1023)];
  __syncthreads();

  float mx[4] = {-3e38f,-3e38f,-3e38f,-3e38f};
  for (int l = tid; l < L_; l += 256) {
    const float* qp = qs + ((size_t)b*L_ + l)*D_;
    float dot[4] = {0,0,0,0};
    for (int dd = 0; dd < D_; dd += 4) {
      f32x4 qv = *(const f32x4*)(qp + dd);
      #pragma unroll
      for (int mi=0; mi<4; ++mi)
        dot[mi] += qv[0]*mem_s[mi][dd] + qv[1]*mem_s[mi][dd+1]
                 + qv[2]*mem_s[mi][dd+2] + qv[3]*mem_s[mi][dd+3];
    }
    #pragma unroll
    for (int mi=0; mi<4; ++mi) { w_lds[mi][l] = dot[mi]; mx[mi] = fmaxf(mx[mi], dot[mi]); }
  }
  float Mv[4], Zv[4];
  for (int mi=0; mi<4; ++mi) {
    redb[tid] = mx[mi]; __syncthreads();
    for (int s=128; s>0; s>>=1) { if (tid<s) redb[tid]=fmaxf(redb[tid],redb[tid+s]); __syncthreads(); }
    Mv[mi] = redb[0]; __syncthreads();
  }
  float sm[4] = {0,0,0,0};
  for (int l = tid; l < L_; l += 256)
    #pragma unroll
    for (int mi=0; mi<4; ++mi) {
      float wv = __expf(w_lds[mi][l] - Mv[mi]);
      w_lds[mi][l] = wv; sm[mi] += wv;
    }
  for (int mi=0; mi<4; ++mi) {
    redb[tid] = sm[mi]; __syncthreads();
    for (int s=128; s>0; s>>=1) { if (tid<s) redb[tid]+=redb[tid+s]; __syncthreads(); }
    Zv[mi] = redb[0]; __syncthreads();
  }
  int d0 = tid*4;
  f32x4 a[4];
  #pragma unroll
  for (int mi=0;mi<4;++mi) a[mi] = (f32x4){0,0,0,0};
  for (int l = 0; l < L_; ++l) {
    f32x4 qv = *(const f32x4*)(qs + ((size_t)b*L_ + l)*D_ + d0);
    #pragma unroll
    for (int mi=0; mi<4; ++mi) a[mi] += qv * w_lds[mi][l];
  }
  #pragma unroll
  for (int mi=0; mi<4; ++mi) {
    float invz = 1.f/Zv[mi];
    #pragma unroll
    for (int c=0; c<4; ++c)
      out[((size_t)b*M_ + m0 + mi)*D_ + d0 + c] = a[mi][c]*invz;
  }
}

extern "C" void kernel_launch(void* const* d_in, const int* in_sizes, int n_in,
                              void* d_out, int out_size, void* d_ws, size_t ws_size,
                              hipStream_t stream) {
  const float* qs  = (const float*)d_in[0];
  const float* mem = (const float*)d_in[1];
  float* out = (float*)d_out;

  // tuple output: r [8*512*1024] then memory [512*1024]
  hipMemcpyAsync(out + (size_t)B_*M_*D_, mem, (size_t)M_*D_*sizeof(float),
                 hipMemcpyDeviceToDevice, stream);

  if (ws_size >= (size_t)WS_NEED) {
    char* base = (char*)d_ws;
    halfT* mem16 = (halfT*)(base + OFF_MEM16);
    halfT* qs16  = (halfT*)(base + OFF_QS16);
    float* S     = (float*)(base + OFF_S);
    halfT* P16   = (halfT*)(base + OFF_P16);
    float* invl  = (float*)(base + OFF_INVL);
    float* rp    = (float*)(base + OFF_RP);    // overlays S (dead after softmax)

    prep_mem16<<<2048, 256, 0, stream>>>(mem, mem16);
    prep_qs16<<<2048, 256, 0, stream>>>(qs, qs16);
    gemm_qk<<<256, 512, 0, stream>>>(mem16, qs16, S);
    softmax_rows<<<4096, 256, 0, stream>>>(S, P16, invl);
    gemm_pv<<<256, 512, 0, stream>>>(P16, qs16, rp);
    combine_scale<<<4096, 256, 0, stream>>>(rp, invl, out);
  } else {
    fallback_kernel<<<1024, 256, 0, stream>>>(qs, mem, out);
  }
}

// Round 11
// 165.635 us; speedup vs baseline: 1.3531x; 1.0605x over previous
//
#include <hip/hip_runtime.h>
#include <hip/hip_fp16.h>

// Memory_Attention: r = softmax_L(memory @ qs^T) @ qs ; out = (r, memory)
// B=8 L=4096 D=1024 M=512, fp32 in/out.
//
// Round 11: kill the 8-way LDS bank conflicts on MFMA frag reads (6.3e6
// conflict cycles/dispatch on both GEMMs). Rows are 64 halfs = 128 B = bank-
// aligned, so ds_read_b128 phases (8 lanes, fixed chunk) were 8-way. Fix via
// PRE-SWIZZLED global fp16 layouts (rule #21: gload_lds dest must stay linear,
// so permute the source): within each 64-half row-window, chunk g (8 halfs)
// stored at position g ^ (row&7). prep_mem16/prep_qs16/softmax write swizzled;
// frag reads XOR with (li&7). pv's reg-transposed B path reads qs16 with the
// inverse XOR; its LDS write scheme (verified 2-way) unchanged.
// Pipeline: prep_mem16 + prep_qs16 -> gemm_qk -> softmax -> gemm_pv(split-K x4)
//           -> combine_scale.  rp overlays S.

#define B_ 8
#define L_ 4096
#define D_ 1024
#define M_ 512

typedef _Float16 halfT;
typedef _Float16 half8 __attribute__((ext_vector_type(8)));
typedef _Float16 half4_t __attribute__((ext_vector_type(4)));
typedef float f32x4 __attribute__((ext_vector_type(4)));

// ---- ws layout (bytes) ----
#define OFF_MEM16 0ull
#define SZ_MEM16  (512ull*1024*2)             //  1,048,576
#define OFF_QS16  (OFF_MEM16 + SZ_MEM16)
#define SZ_QS16   (8ull*4096*1024*2)          // 67,108,864
#define OFF_S     (OFF_QS16 + SZ_QS16)
#define SZ_S      (8ull*512*4096*4)           // 67,108,864
#define OFF_P16   (OFF_S + SZ_S)
#define SZ_P16    (8ull*512*4096*2)           // 33,554,432
#define OFF_INVL  (OFF_P16 + SZ_P16)
#define SZ_INVL   (8ull*512*4)
#define WS_NEED   (OFF_INVL + SZ_INVL)        // ~168.8 MB (ws known >= 202 MB)
#define OFF_RP    OFF_S                       // overlay: S dead after softmax

#define SWZ(n) ((((n)&7) ^ (((n)>>5)&7)))

__device__ __forceinline__ void gload_lds16(const halfT* g, halfT* l) {
  __builtin_amdgcn_global_load_lds(
      (const __attribute__((address_space(1))) unsigned int*)(const void*)g,
      (__attribute__((address_space(3))) unsigned int*)l, 16, 0, 0);
}

// ---------------- prep: streaming fp32 -> fp16, row-chunk pre-swizzle ----------------
// Element layout: row-major [R][1024], but within each 64-half window the
// 8-half chunk g lives at position g ^ (row&7).
__global__ __launch_bounds__(256)
void prep_mem16(const float* __restrict__ mem, halfT* __restrict__ mem16) {
  int i8 = blockIdx.x*256 + threadIdx.x;     // half8 index; grid 256 -> 65536 exact
  int row = i8 >> 7, c = i8 & 127;
  int kt = c >> 3, g = c & 7;
  const float* src = mem + (size_t)i8*8;
  f32x4 x0 = *(const f32x4*)src;
  f32x4 x1 = *(const f32x4*)(src + 4);
  half8 h;
  #pragma unroll
  for (int j = 0; j < 4; ++j) { h[j] = (halfT)x0[j]; h[4+j] = (halfT)x1[j]; }
  *(half8*)&mem16[(size_t)row*1024 + kt*64 + ((g ^ (row & 7)) << 3)] = h;
}

__global__ __launch_bounds__(256)
void prep_qs16(const float* __restrict__ qs, halfT* __restrict__ q16) {
  size_t base = (size_t)blockIdx.x*256 + threadIdx.x;
  #pragma unroll
  for (int it = 0; it < 8; ++it) {
    size_t i8 = base + (size_t)it*524288;     // half8 index (4,194,304 total)
    size_t row = i8 >> 7;
    int c = (int)(i8 & 127);
    int kt = c >> 3, g = c & 7;
    const float* src = qs + i8*8;
    f32x4 x0 = *(const f32x4*)src;
    f32x4 x1 = *(const f32x4*)(src + 4);
    half8 h;
    #pragma unroll
    for (int j = 0; j < 4; ++j) { h[j] = (halfT)x0[j]; h[4+j] = (halfT)x1[j]; }
    *(half8*)&q16[row*1024 + kt*64 + ((g ^ ((int)row & 7)) << 3)] = h;
  }
}

// ---------------- gemm_qk: S[b][512][4096] = mem16 @ qs16^T ----------------
// 256^2 tile, BK=64, 8 waves, 2-phase dbuf, both operands via global_load_lds
// (linear dest; source pre-swizzled). Frag reads XOR chunk with (li&7).
__global__ __launch_bounds__(512, 2)
void gemm_qk(const halfT* __restrict__ mem16, const halfT* __restrict__ qs16,
             float* __restrict__ S)
{
  __shared__ __attribute__((aligned(16))) halfT At[2][256*64];   // 64 KB
  __shared__ __attribute__((aligned(16))) halfT Bt[2][256*64];   // 64 KB

  int bid = blockIdx.x;                      // 256
  int swz = (bid & 7)*32 + (bid >> 3);       // XCD-contiguous
  int b   = swz >> 5;                        // one b per XCD
  int rem = swz & 31;
  int nt  = rem >> 1;
  int mt  = rem & 1;

  int tid = threadIdx.x;
  int w = tid >> 6, lane = tid & 63, lg = lane >> 4, li = lane & 15;
  int wm = w >> 2, wn = w & 3;
  int sl = li & 7;                           // row&7 of every frag row this lane reads
  int rA = tid >> 3;
  int cA = (tid & 7)*8;

  const halfT* Ab = mem16 + (size_t)mt*256*1024;
  const halfT* Bb = qs16 + ((size_t)b*L_ + nt*256)*D_;

  f32x4 acc[8][4];
  #pragma unroll
  for (int i=0;i<8;++i)
    #pragma unroll
    for (int j=0;j<4;++j) acc[i][j] = (f32x4){0.f,0.f,0.f,0.f};

#define STAGE_QK(nb_, kt_)                                                     \
  do {                                                                         \
    const halfT* a0 = Ab + (size_t)(kt_)*64 + cA;                              \
    const halfT* b0 = Bb + (size_t)(kt_)*64 + cA;                              \
    _Pragma("unroll")                                                          \
    for (int j = 0; j < 4; ++j) {                                              \
      int r = rA + j*64;                                                       \
      gload_lds16(a0 + (size_t)r*1024, &At[nb_][(tid + j*512)*8]);             \
      gload_lds16(b0 + (size_t)r*1024, &Bt[nb_][(tid + j*512)*8]);             \
    }                                                                          \
  } while (0)

  STAGE_QK(0, 0);
  __syncthreads();                           // prologue drain

  int nb = 0;
  for (int kt = 0; kt < 16; ++kt) {
    if (kt + 1 < 16) STAGE_QK(nb ^ 1, kt + 1);
    #pragma unroll
    for (int ksub = 0; ksub < 2; ++ksub) {
      int gx = ((ksub*4 + lg) ^ sl) << 3;    // swizzled chunk byte-group
      half8 Af[8], Bf[4];
      #pragma unroll
      for (int mf = 0; mf < 8; ++mf)
        Af[mf] = *(const half8*)&At[nb][(wm*128 + mf*16 + li)*64 + gx];
      #pragma unroll
      for (int nf = 0; nf < 4; ++nf)
        Bf[nf] = *(const half8*)&Bt[nb][(wn*64 + nf*16 + li)*64 + gx];
      #pragma unroll
      for (int mf = 0; mf < 8; ++mf)
        #pragma unroll
        for (int nf = 0; nf < 4; ++nf)
          acc[mf][nf] = __builtin_amdgcn_mfma_f32_16x16x32_f16(Af[mf], Bf[nf], acc[mf][nf], 0,0,0);
    }
    __syncthreads();
    nb ^= 1;
  }
#undef STAGE_QK

  float* Cb = S + (size_t)b*M_*L_;
  int colbase = nt*256 + wn*64;
  #pragma unroll
  for (int mf = 0; mf < 8; ++mf) {
    #pragma unroll
    for (int r = 0; r < 4; ++r) {
      int row = mt*256 + wm*128 + mf*16 + lg*4 + r;
      #pragma unroll
      for (int nf = 0; nf < 4; ++nf)
        Cb[(size_t)row*L_ + colbase + nf*16 + li] = acc[mf][nf][r];
    }
  }
}

// ---------------- gemm_pv: rp[ks][b][512][1024] = P16 @ qs16 (K-chunk ks) ----------------
// A=P16 (pre-swizzled) via gload_lds, frag reads XOR'd. B=qs16 reg-staged
// in-LDS transpose; source reads apply inverse pre-swizzle; LDS write/read
// scheme (SWZ(n), verified 2-way) unchanged.
__global__ __launch_bounds__(512, 2)
void gemm_pv(const halfT* __restrict__ P16, const halfT* __restrict__ qs16,
             float* __restrict__ rp)
{
  __shared__ __attribute__((aligned(16))) halfT At[2][256*64];   // 64 KB
  __shared__ __attribute__((aligned(16))) halfT Bt[2][256*64];   // 64 KB

  int bid = blockIdx.x;                      // 256
  int swz = (bid & 7)*32 + (bid >> 3);
  int ks  = swz >> 6;                        // 0..3
  int rem = swz & 63;
  int b   = rem >> 3;
  int nt  = (rem >> 1) & 3;
  int mt  = rem & 1;

  int tid = threadIdx.x;
  int w = tid >> 6, lane = tid & 63, lg = lane >> 4, li = lane & 15;
  int wm = w >> 2, wn = w & 3;
  int sl = li & 7;

  const halfT* Ab = P16 + (size_t)b*M_*L_ + (size_t)mt*256*L_ + ks*1024;
  const halfT* Bb = qs16 + ((size_t)b*L_ + ks*1024)*D_ + nt*256;
  int krow = tid >> 3;                       // 0..63
  int seg  = tid & 7;
  int rs   = krow & 7;                       // source row&7 for inverse swizzle

  f32x4 acc[8][4];
  #pragma unroll
  for (int i=0;i<8;++i)
    #pragma unroll
    for (int j=0;j<4;++j) acc[i][j] = (f32x4){0.f,0.f,0.f,0.f};

  half8 hx[4];

#define GLOADB_PV(kt_)                                                         \
  do {                                                                         \
    const halfT* rowp = Bb + (size_t)((kt_)*64 + krow)*D_ + (seg >> 1)*64;     \
    _Pragma("unroll")                                                          \
    for (int j = 0; j < 4; ++j)                                                \
      hx[j] = *(const half8*)(rowp + ((((seg & 1)*4 + j) ^ rs) << 3));         \
  } while (0)

#define STAGEA_PV(nb_, kt_)                                                    \
  do {                                                                         \
    const halfT* a0 = Ab + (size_t)(kt_)*64 + (tid & 7)*8;                     \
    _Pragma("unroll")                                                          \
    for (int j = 0; j < 4; ++j)                                                \
      gload_lds16(a0 + (size_t)((tid >> 3) + j*64)*L_, &At[nb_][(tid + j*512)*8]); \
  } while (0)

#define WRITEB_PV(nb_)                                                         \
  do {                                                                         \
    _Pragma("unroll")                                                          \
    for (int i = 0; i < 32; ++i) {                                             \
      int n_ = seg*32 + i;                                                     \
      Bt[nb_][n_*64 + ((((krow >> 3) ^ SWZ(n_)) << 3)) + (krow & 7)] =         \
          hx[i >> 3][i & 7];                                                   \
    }                                                                          \
  } while (0)

  GLOADB_PV(0);
  STAGEA_PV(0, 0);
  WRITEB_PV(0);
  __syncthreads();

  int nb = 0;
  for (int kt = 0; kt < 16; ++kt) {
    if (kt + 1 < 16) { GLOADB_PV(kt + 1); STAGEA_PV(nb ^ 1, kt + 1); }
    #pragma unroll
    for (int ksub = 0; ksub < 2; ++ksub) {
      int gx = ((ksub*4 + lg) ^ sl) << 3;
      half8 Af[8], Bf[4];
      #pragma unroll
      for (int mf = 0; mf < 8; ++mf)
        Af[mf] = *(const half8*)&At[nb][(wm*128 + mf*16 + li)*64 + gx];
      #pragma unroll
      for (int nf = 0; nf < 4; ++nf) {
        int n_ = wn*64 + nf*16 + li;
        Bf[nf] = *(const half8*)&Bt[nb][n_*64 + (((ksub*4 + lg) ^ SWZ(n_)) << 3)];
      }
      #pragma unroll
      for (int mf = 0; mf < 8; ++mf)
        #pragma unroll
        for (int nf = 0; nf < 4; ++nf)
          acc[mf][nf] = __builtin_amdgcn_mfma_f32_16x16x32_f16(Af[mf], Bf[nf], acc[mf][nf], 0,0,0);
    }
    if (kt + 1 < 16) WRITEB_PV(nb ^ 1);      // after compute: loads have landed
    __syncthreads();
    nb ^= 1;
  }
#undef GLOADB_PV
#undef STAGEA_PV
#undef WRITEB_PV

  float* Cb = rp + (size_t)ks*((size_t)B_*M_*D_) + (size_t)b*M_*D_;
  int colbase = nt*256 + wn*64;
  #pragma unroll
  for (int mf = 0; mf < 8; ++mf) {
    #pragma unroll
    for (int r = 0; r < 4; ++r) {
      int row = mt*256 + wm*128 + mf*16 + lg*4 + r;
      #pragma unroll
      for (int nf = 0; nf < 4; ++nf)
        Cb[(size_t)row*D_ + colbase + nf*16 + li] = acc[mf][nf][r];
    }
  }
}

// ---------------- row softmax: P16 = exp(S - max) [pre-swizzled], invl = 1/sum ----------------
__global__ __launch_bounds__(256)
void softmax_rows(const float* __restrict__ S, halfT* __restrict__ P,
                  float* __restrict__ invl)
{
  __shared__ float red[4];
  int row = blockIdx.x;                    // 0..4095 = b*512+m
  int rs  = row & 7;
  int tid = threadIdx.x;
  const float* src = S + (size_t)row*L_;
  f32x4 v[4];
  float mx = -3.0e38f;
  #pragma unroll
  for (int i = 0; i < 4; ++i) {
    v[i] = *(const f32x4*)&src[(size_t)(i*256 + tid)*4];
    #pragma unroll
    for (int e = 0; e < 4; ++e) mx = fmaxf(mx, v[i][e]);
  }
  #pragma unroll
  for (int off = 1; off < 64; off <<= 1) mx = fmaxf(mx, __shfl_xor(mx, off));
  int w = tid >> 6;
  if ((tid & 63) == 0) red[w] = mx;
  __syncthreads();
  mx = fmaxf(fmaxf(red[0], red[1]), fmaxf(red[2], red[3]));

  float sum = 0.f;
  halfT* dst = P + (size_t)row*L_;
  #pragma unroll
  for (int i = 0; i < 4; ++i) {
    half4_t h;
    #pragma unroll
    for (int e = 0; e < 4; ++e) {
      float ev = __expf(v[i][e] - mx);
      sum += ev;
      h[e] = (halfT)ev;
    }
    int idx4 = i*256 + tid;                // which half4 of the row
    int kt = idx4 >> 4, g = (idx4 >> 1) & 7, o = idx4 & 1;
    *(half4_t*)&dst[kt*64 + ((g ^ rs) << 3) + o*4] = h;
  }
  #pragma unroll
  for (int off = 1; off < 64; off <<= 1) sum += __shfl_xor(sum, off);
  __syncthreads();
  if ((tid & 63) == 0) red[w] = sum;
  __syncthreads();
  if (tid == 0) invl[row] = 1.0f / (red[0] + red[1] + red[2] + red[3]);
}

// ---------------- combine: out = invl * sum_ks rp[ks] ----------------
__global__ __launch_bounds__(256)
void combine_scale(const float* __restrict__ rp, const float* __restrict__ invl,
                   float* __restrict__ out)
{
  int bm = blockIdx.x;                     // 0..4095
  int tid = threadIdx.x;
  size_t off = (size_t)bm*D_ + tid*4;
  f32x4 v = *(const f32x4*)&rp[off];
  #pragma unroll
  for (int s = 1; s < 4; ++s)
    v += *(const f32x4*)&rp[(size_t)s*B_*M_*D_ + off];
  float sc = invl[bm];
  v *= sc;
  *(f32x4*)&out[off] = v;
}

// ---------------- fallback (tiny ws): correct, slow fp32 ----------------
__global__ void fallback_kernel(const float* __restrict__ qs,
                                const float* __restrict__ mem,
                                float* __restrict__ out)
{
  __shared__ float w_lds[4][4096];
  __shared__ float mem_s[4][1024];
  __shared__ float redb[256];
  int blk = blockIdx.x;
  int b = blk >> 7;
  int m0 = (blk & 127)*4;
  int tid = threadIdx.x;

  for (int i = tid; i < 4*1024; i += 256)
    mem_s[i>>10][i&1023] = mem[(size_t)(m0 + (i>>10))*D_ + (i&1023)];
  __syncthreads();

  float mx[4] = {-3e38f,-3e38f,-3e38f,-3e38f};
  for (int l = tid; l < L_; l += 256) {
    const float* qp = qs + ((size_t)b*L_ + l)*D_;
    float dot[4] = {0,0,0,0};
    for (int dd = 0; dd < D_; dd += 4) {
      f32x4 qv = *(const f32x4*)(qp + dd);
      #pragma unroll
      for (int mi=0; mi<4; ++mi)
        dot[mi] += qv[0]*mem_s[mi][dd] + qv[1]*mem_s[mi][dd+1]
                 + qv[2]*mem_s[mi][dd+2] + qv[3]*mem_s[mi][dd+3];
    }
    #pragma unroll
    for (int mi=0; mi<4; ++mi) { w_lds[mi][l] = dot[mi]; mx[mi] = fmaxf(mx[mi], dot[mi]); }
  }
  float Mv[4], Zv[4];
  for (int mi=0; mi<4; ++mi) {
    redb[tid] = mx[mi]; __syncthreads();
    for (int s=128; s>0; s>>=1) { if (tid<s) redb[tid]=fmaxf(redb[tid],redb[tid+s]); __syncthreads(); }
    Mv[mi] = redb[0]; __syncthreads();
  }
  float sm[4] = {0,0,0,0};
  for (int l = tid; l < L_; l += 256)
    #pragma unroll
    for (int mi=0; mi<4; ++mi) {
      float wv = __expf(w_lds[mi][l] - Mv[mi]);
      w_lds[mi][l] = wv; sm[mi] += wv;
    }
  for (int mi=0; mi<4; ++mi) {
    redb[tid] = sm[mi]; __syncthreads();
    for (int s=128; s>0; s>>=1) { if (tid<s) redb[tid]+=redb[tid+s]; __syncthreads(); }
    Zv[mi] = redb[0]; __syncthreads();
  }
  int d0 = tid*4;
  f32x4 a[4];
  #pragma unroll
  for (int mi=0;mi<4;++mi) a[mi] = (f32x4){0,0,0,0};
  for (int l = 0; l < L_; ++l) {
    f32x4 qv = *(const f32x4*)(qs + ((size_t)b*L_ + l)*D_ + d0);
    #pragma unroll
    for (int mi=0; mi<4; ++mi) a[mi] += qv * w_lds[mi][l];
  }
  #pragma unroll
  for (int mi=0; mi<4; ++mi) {
    float invz = 1.f/Zv[mi];
    #pragma unroll
    for (int c=0; c<4; ++c)
      out[((size_t)b*M_ + m0 + mi)*D_ + d0 + c] = a[mi][c]*invz;
  }
}

extern "C" void kernel_launch(void* const* d_in, const int* in_sizes, int n_in,
                              void* d_out, int out_size, void* d_ws, size_t ws_size,
                              hipStream_t stream) {
  const float* qs  = (const float*)d_in[0];
  const float* mem = (const float*)d_in[1];
  float* out = (float*)d_out;

  // tuple output: r [8*512*1024] then memory [512*1024]
  hipMemcpyAsync(out + (size_t)B_*M_*D_, mem, (size_t)M_*D_*sizeof(float),
                 hipMemcpyDeviceToDevice, stream);

  if (ws_size >= (size_t)WS_NEED) {
    char* base = (char*)d_ws;
    halfT* mem16 = (halfT*)(base + OFF_MEM16);
    halfT* qs16  = (halfT*)(base + OFF_QS16);
    float* S     = (float*)(base + OFF_S);
    halfT* P16   = (halfT*)(base + OFF_P16);
    float* invl  = (float*)(base + OFF_INVL);
    float* rp    = (float*)(base + OFF_RP);    // overlays S (dead after softmax)

    prep_mem16<<<256, 256, 0, stream>>>(mem, mem16);
    prep_qs16<<<2048, 256, 0, stream>>>(qs, qs16);
    gemm_qk<<<256, 512, 0, stream>>>(mem16, qs16, S);
    softmax_rows<<<4096, 256, 0, stream>>>(S, P16, invl);
    gemm_pv<<<256, 512, 0, stream>>>(P16, qs16, rp);
    combine_scale<<<4096, 256, 0, stream>>>(rp, invl, out);
  } else {
    fallback_kernel<<<1024, 256, 0, stream>>>(qs, mem, out);
  }
}

// Round 12
// 158.431 us; speedup vs baseline: 1.4146x; 1.0455x over previous
//
#include <hip/hip_runtime.h>
#include <hip/hip_fp16.h>

// Memory_Attention: r = softmax_L(memory @ qs^T) @ qs ; out = (r, memory)
// B=8 L=4096 D=1024 M=512, fp32 in/out.
//
// Round 12: T4 counted-vmcnt pipeline in both GEMM K-loops (replaces the
// __syncthreads vmcnt(0) drain). Invariant: each wave issues exactly 8
// global_load_lds per K-tile in tile order, so per-wave `s_waitcnt vmcnt(8)`
// + s_barrier proves tile t+1 is fully in LDS while tile t+2's 8 loads stay
// in flight ACROSS the barrier (m218 mechanism). Loop shape:
//   compute(buf[t&1])                         // reads complete via data-dep
//   s_barrier (B2)                            // all waves' reads of buf done
//   stage(buf[t&1], t+2)                      // overwrite just-freed buffer
//   s_waitcnt vmcnt(8) lgkmcnt(0); sched_barrier(0)   // t+1 landed, t+2 in flight
//   s_barrier (B1)
// Everything else identical to round 11 (pre-swizzled fp16 layouts, no LDS
// bank conflicts on frag reads).
// Pipeline: prep_mem16 + prep_qs16 -> gemm_qk -> softmax -> gemm_pv(split-K x4)
//           -> combine_scale.  rp overlays S.

#define B_ 8
#define L_ 4096
#define D_ 1024
#define M_ 512

typedef _Float16 halfT;
typedef _Float16 half8 __attribute__((ext_vector_type(8)));
typedef _Float16 half4_t __attribute__((ext_vector_type(4)));
typedef float f32x4 __attribute__((ext_vector_type(4)));

// ---- ws layout (bytes) ----
#define OFF_MEM16 0ull
#define SZ_MEM16  (512ull*1024*2)             //  1,048,576
#define OFF_QS16  (OFF_MEM16 + SZ_MEM16)
#define SZ_QS16   (8ull*4096*1024*2)          // 67,108,864
#define OFF_S     (OFF_QS16 + SZ_QS16)
#define SZ_S      (8ull*512*4096*4)           // 67,108,864
#define OFF_P16   (OFF_S + SZ_S)
#define SZ_P16    (8ull*512*4096*2)           // 33,554,432
#define OFF_INVL  (OFF_P16 + SZ_P16)
#define SZ_INVL   (8ull*512*4)
#define WS_NEED   (OFF_INVL + SZ_INVL)        // ~168.8 MB (ws known >= 202 MB)
#define OFF_RP    OFF_S                       // overlay: S dead after softmax

#define SWZ(n) ((((n)&7) ^ (((n)>>5)&7)))

__device__ __forceinline__ void gload_lds16(const halfT* g, halfT* l) {
  __builtin_amdgcn_global_load_lds(
      (const __attribute__((address_space(1))) unsigned int*)(const void*)g,
      (__attribute__((address_space(3))) unsigned int*)l, 16, 0, 0);
}

// ---------------- prep: streaming fp32 -> fp16, row-chunk pre-swizzle ----------------
// Row-major [R][1024]; within each 64-half window, chunk g lives at g ^ (row&7).
__global__ __launch_bounds__(256)
void prep_mem16(const float* __restrict__ mem, halfT* __restrict__ mem16) {
  int i8 = blockIdx.x*256 + threadIdx.x;     // half8 index; grid 256 -> 65536 exact
  int row = i8 >> 7, c = i8 & 127;
  int kt = c >> 3, g = c & 7;
  const float* src = mem + (size_t)i8*8;
  f32x4 x0 = *(const f32x4*)src;
  f32x4 x1 = *(const f32x4*)(src + 4);
  half8 h;
  #pragma unroll
  for (int j = 0; j < 4; ++j) { h[j] = (halfT)x0[j]; h[4+j] = (halfT)x1[j]; }
  *(half8*)&mem16[(size_t)row*1024 + kt*64 + ((g ^ (row & 7)) << 3)] = h;
}

__global__ __launch_bounds__(256)
void prep_qs16(const float* __restrict__ qs, halfT* __restrict__ q16) {
  size_t base = (size_t)blockIdx.x*256 + threadIdx.x;
  #pragma unroll
  for (int it = 0; it < 8; ++it) {
    size_t i8 = base + (size_t)it*524288;     // half8 index (4,194,304 total)
    size_t row = i8 >> 7;
    int c = (int)(i8 & 127);
    int kt = c >> 3, g = c & 7;
    const float* src = qs + i8*8;
    f32x4 x0 = *(const f32x4*)src;
    f32x4 x1 = *(const f32x4*)(src + 4);
    half8 h;
    #pragma unroll
    for (int j = 0; j < 4; ++j) { h[j] = (halfT)x0[j]; h[4+j] = (halfT)x1[j]; }
    *(half8*)&q16[row*1024 + kt*64 + ((g ^ ((int)row & 7)) << 3)] = h;
  }
}

// ---------------- gemm_qk: S[b][512][4096] = mem16 @ qs16^T ----------------
// 256^2 tile, BK=64, 8 waves, dbuf + counted-vmcnt pipeline. Per b: MT=2, NT=16.
__global__ __launch_bounds__(512, 2)
void gemm_qk(const halfT* __restrict__ mem16, const halfT* __restrict__ qs16,
             float* __restrict__ S)
{
  __shared__ __attribute__((aligned(16))) halfT At[2][256*64];   // 64 KB
  __shared__ __attribute__((aligned(16))) halfT Bt[2][256*64];   // 64 KB

  int bid = blockIdx.x;                      // 256
  int swz = (bid & 7)*32 + (bid >> 3);       // XCD-contiguous
  int b   = swz >> 5;                        // one b per XCD
  int rem = swz & 31;
  int nt  = rem >> 1;
  int mt  = rem & 1;

  int tid = threadIdx.x;
  int w = tid >> 6, lane = tid & 63, lg = lane >> 4, li = lane & 15;
  int wm = w >> 2, wn = w & 3;
  int sl = li & 7;                           // row&7 of every frag row this lane reads
  int rA = tid >> 3;
  int cA = (tid & 7)*8;

  const halfT* Ab = mem16 + (size_t)mt*256*1024;
  const halfT* Bb = qs16 + ((size_t)b*L_ + nt*256)*D_;

  f32x4 acc[8][4];
  #pragma unroll
  for (int i=0;i<8;++i)
    #pragma unroll
    for (int j=0;j<4;++j) acc[i][j] = (f32x4){0.f,0.f,0.f,0.f};

// 8 gload_lds per thread = 8 vm-instructions per wave per tile (vmcnt unit).
#define STAGE_QK(nb_, kt_)                                                     \
  do {                                                                         \
    const halfT* a0 = Ab + (size_t)(kt_)*64 + cA;                              \
    const halfT* b0 = Bb + (size_t)(kt_)*64 + cA;                              \
    _Pragma("unroll")                                                          \
    for (int j = 0; j < 4; ++j) {                                              \
      int r = rA + j*64;                                                       \
      gload_lds16(a0 + (size_t)r*1024, &At[nb_][(tid + j*512)*8]);             \
      gload_lds16(b0 + (size_t)r*1024, &Bt[nb_][(tid + j*512)*8]);             \
    }                                                                          \
  } while (0)

#define COMPUTE_QK(nb_)                                                        \
  do {                                                                         \
    _Pragma("unroll")                                                          \
    for (int ksub = 0; ksub < 2; ++ksub) {                                     \
      int gx = ((ksub*4 + lg) ^ sl) << 3;                                      \
      half8 Af[8], Bf[4];                                                      \
      _Pragma("unroll")                                                        \
      for (int mf = 0; mf < 8; ++mf)                                           \
        Af[mf] = *(const half8*)&At[nb_][(wm*128 + mf*16 + li)*64 + gx];       \
      _Pragma("unroll")                                                        \
      for (int nf = 0; nf < 4; ++nf)                                           \
        Bf[nf] = *(const half8*)&Bt[nb_][(wn*64 + nf*16 + li)*64 + gx];        \
      _Pragma("unroll")                                                        \
      for (int mf = 0; mf < 8; ++mf)                                           \
        _Pragma("unroll")                                                      \
        for (int nf = 0; nf < 4; ++nf)                                         \
          acc[mf][nf] = __builtin_amdgcn_mfma_f32_16x16x32_f16(Af[mf], Bf[nf], acc[mf][nf], 0,0,0); \
    }                                                                          \
  } while (0)

  // Prologue: tiles 0 and 1 in flight; wait only tile 0 (vmcnt(8)).
  STAGE_QK(0, 0);
  STAGE_QK(1, 1);
  asm volatile("s_waitcnt vmcnt(8)" ::: "memory");
  __builtin_amdgcn_sched_barrier(0);
  __builtin_amdgcn_s_barrier();

  for (int kt = 0; kt < 16; ++kt) {
    COMPUTE_QK(kt & 1);
    __builtin_amdgcn_s_barrier();            // B2: all reads of buf[kt&1] done
    if (kt + 2 < 16) {
      STAGE_QK(kt & 1, kt + 2);              // overwrite just-freed buffer
      asm volatile("s_waitcnt vmcnt(8) lgkmcnt(0)" ::: "memory");
    } else {
      asm volatile("s_waitcnt vmcnt(0) lgkmcnt(0)" ::: "memory");
    }
    __builtin_amdgcn_sched_barrier(0);
    __builtin_amdgcn_s_barrier();            // B1: tile kt+1 fully in LDS
  }
#undef STAGE_QK
#undef COMPUTE_QK

  float* Cb = S + (size_t)b*M_*L_;
  int colbase = nt*256 + wn*64;
  #pragma unroll
  for (int mf = 0; mf < 8; ++mf) {
    #pragma unroll
    for (int r = 0; r < 4; ++r) {
      int row = mt*256 + wm*128 + mf*16 + lg*4 + r;
      #pragma unroll
      for (int nf = 0; nf < 4; ++nf)
        Cb[(size_t)row*L_ + colbase + nf*16 + li] = acc[mf][nf][r];
    }
  }
}

// ---------------- gemm_pv: rp[ks][b][512][1024] = P16 @ qs16 (K-chunk ks) ----------------
// A=P16 (pre-swizzled) via gload_lds with counted vmcnt; B=qs16 reg-staged
// in-LDS transpose (WRITEB after B2; compiler emits counted waits for bx).
__global__ __launch_bounds__(512, 2)
void gemm_pv(const halfT* __restrict__ P16, const halfT* __restrict__ qs16,
             float* __restrict__ rp)
{
  __shared__ __attribute__((aligned(16))) halfT At[2][256*64];   // 64 KB
  __shared__ __attribute__((aligned(16))) halfT Bt[2][256*64];   // 64 KB

  int bid = blockIdx.x;                      // 256
  int swz = (bid & 7)*32 + (bid >> 3);
  int ks  = swz >> 6;                        // 0..3
  int rem = swz & 63;
  int b   = rem >> 3;
  int nt  = (rem >> 1) & 3;
  int mt  = rem & 1;

  int tid = threadIdx.x;
  int w = tid >> 6, lane = tid & 63, lg = lane >> 4, li = lane & 15;
  int wm = w >> 2, wn = w & 3;
  int sl = li & 7;

  const halfT* Ab = P16 + (size_t)b*M_*L_ + (size_t)mt*256*L_ + ks*1024;
  const halfT* Bb = qs16 + ((size_t)b*L_ + ks*1024)*D_ + nt*256;
  int krow = tid >> 3;                       // 0..63
  int seg  = tid & 7;
  int rs   = krow & 7;                       // source row&7 for inverse swizzle

  f32x4 acc[8][4];
  #pragma unroll
  for (int i=0;i<8;++i)
    #pragma unroll
    for (int j=0;j<4;++j) acc[i][j] = (f32x4){0.f,0.f,0.f,0.f};

  half8 hx[4];

#define GLOADB_PV(kt_)                                                         \
  do {                                                                         \
    const halfT* rowp = Bb + (size_t)((kt_)*64 + krow)*D_ + (seg >> 1)*64;     \
    _Pragma("unroll")                                                          \
    for (int j = 0; j < 4; ++j)                                                \
      hx[j] = *(const half8*)(rowp + ((((seg & 1)*4 + j) ^ rs) << 3));         \
  } while (0)

// 4 gload_lds per thread per tile (A-side vmcnt unit).
#define STAGEA_PV(nb_, kt_)                                                    \
  do {                                                                         \
    const halfT* a0 = Ab + (size_t)(kt_)*64 + (tid & 7)*8;                     \
    _Pragma("unroll")                                                          \
    for (int j = 0; j < 4; ++j)                                                \
      gload_lds16(a0 + (size_t)((tid >> 3) + j*64)*L_, &At[nb_][(tid + j*512)*8]); \
  } while (0)

#define WRITEB_PV(nb_)                                                         \
  do {                                                                         \
    _Pragma("unroll")                                                          \
    for (int i = 0; i < 32; ++i) {                                             \
      int n_ = seg*32 + i;                                                     \
      Bt[nb_][n_*64 + ((((krow >> 3) ^ SWZ(n_)) << 3)) + (krow & 7)] =         \
          hx[i >> 3][i & 7];                                                   \
    }                                                                          \
  } while (0)

#define COMPUTE_PV(nb_)                                                        \
  do {                                                                         \
    _Pragma("unroll")                                                          \
    for (int ksub = 0; ksub < 2; ++ksub) {                                     \
      int gx = ((ksub*4 + lg) ^ sl) << 3;                                      \
      half8 Af[8], Bf[4];                                                      \
      _Pragma("unroll")                                                        \
      for (int mf = 0; mf < 8; ++mf)                                           \
        Af[mf] = *(const half8*)&At[nb_][(wm*128 + mf*16 + li)*64 + gx];       \
      _Pragma("unroll")                                                        \
      for (int nf = 0; nf < 4; ++nf) {                                         \
        int n_ = wn*64 + nf*16 + li;                                           \
        Bf[nf] = *(const half8*)&Bt[nb_][n_*64 + (((ksub*4 + lg) ^ SWZ(n_)) << 3)]; \
      }                                                                        \
      _Pragma("unroll")                                                        \
      for (int mf = 0; mf < 8; ++mf)                                           \
        _Pragma("unroll")                                                      \
        for (int nf = 0; nf < 4; ++nf)                                         \
          acc[mf][nf] = __builtin_amdgcn_mfma_f32_16x16x32_f16(Af[mf], Bf[nf], acc[mf][nf], 0,0,0); \
    }                                                                          \
  } while (0)

  // Prologue: A tiles 0,1 in flight; B tile 0 written; bx <- tile 1.
  GLOADB_PV(0);
  STAGEA_PV(0, 0);
  STAGEA_PV(1, 1);
  WRITEB_PV(0);                              // compiler-counted wait for bx(0)
  GLOADB_PV(1);
  asm volatile("s_waitcnt vmcnt(8) lgkmcnt(0)" ::: "memory");   // A(0) landed; writes(0) done
  __builtin_amdgcn_sched_barrier(0);
  __builtin_amdgcn_s_barrier();

  for (int kt = 0; kt < 16; ++kt) {
    COMPUTE_PV(kt & 1);
    __builtin_amdgcn_s_barrier();            // B2: all reads of tile kt done
    if (kt + 1 < 16) WRITEB_PV((kt + 1) & 1);   // bx(kt+1) -> B-LDS (freed by B2 of kt-1)
    if (kt + 2 < 16) {
      GLOADB_PV(kt + 2);                     // bx <- tile kt+2
      STAGEA_PV(kt & 1, kt + 2);             // A tile kt+2 into freed buffer
      asm volatile("s_waitcnt vmcnt(8) lgkmcnt(0)" ::: "memory");  // A(kt+1) landed; writes visible
    } else {
      asm volatile("s_waitcnt vmcnt(0) lgkmcnt(0)" ::: "memory");
    }
    __builtin_amdgcn_sched_barrier(0);
    __builtin_amdgcn_s_barrier();            // B1
  }
#undef GLOADB_PV
#undef STAGEA_PV
#undef WRITEB_PV
#undef COMPUTE_PV

  float* Cb = rp + (size_t)ks*((size_t)B_*M_*D_) + (size_t)b*M_*D_;
  int colbase = nt*256 + wn*64;
  #pragma unroll
  for (int mf = 0; mf < 8; ++mf) {
    #pragma unroll
    for (int r = 0; r < 4; ++r) {
      int row = mt*256 + wm*128 + mf*16 + lg*4 + r;
      #pragma unroll
      for (int nf = 0; nf < 4; ++nf)
        Cb[(size_t)row*D_ + colbase + nf*16 + li] = acc[mf][nf][r];
    }
  }
}

// ---------------- row softmax: P16 = exp(S - max) [pre-swizzled], invl = 1/sum ----------------
__global__ __launch_bounds__(256)
void softmax_rows(const float* __restrict__ S, halfT* __restrict__ P,
                  float* __restrict__ invl)
{
  __shared__ float red[4];
  int row = blockIdx.x;                    // 0..4095 = b*512+m
  int rs  = row & 7;
  int tid = threadIdx.x;
  const float* src = S + (size_t)row*L_;
  f32x4 v[4];
  float mx = -3.0e38f;
  #pragma unroll
  for (int i = 0; i < 4; ++i) {
    v[i] = *(const f32x4*)&src[(size_t)(i*256 + tid)*4];
    #pragma unroll
    for (int e = 0; e < 4; ++e) mx = fmaxf(mx, v[i][e]);
  }
  #pragma unroll
  for (int off = 1; off < 64; off <<= 1) mx = fmaxf(mx, __shfl_xor(mx, off));
  int w = tid >> 6;
  if ((tid & 63) == 0) red[w] = mx;
  __syncthreads();
  mx = fmaxf(fmaxf(red[0], red[1]), fmaxf(red[2], red[3]));

  float sum = 0.f;
  halfT* dst = P + (size_t)row*L_;
  #pragma unroll
  for (int i = 0; i < 4; ++i) {
    half4_t h;
    #pragma unroll
    for (int e = 0; e < 4; ++e) {
      float ev = __expf(v[i][e] - mx);
      sum += ev;
      h[e] = (halfT)ev;
    }
    int idx4 = i*256 + tid;                // which half4 of the row
    int kt = idx4 >> 4, g = (idx4 >> 1) & 7, o = idx4 & 1;
    *(half4_t*)&dst[kt*64 + ((g ^ rs) << 3) + o*4] = h;
  }
  #pragma unroll
  for (int off = 1; off < 64; off <<= 1) sum += __shfl_xor(sum, off);
  __syncthreads();
  if ((tid & 63) == 0) red[w] = sum;
  __syncthreads();
  if (tid == 0) invl[row] = 1.0f / (red[0] + red[1] + red[2] + red[3]);
}

// ---------------- combine: out = invl * sum_ks rp[ks] ----------------
__global__ __launch_bounds__(256)
void combine_scale(const float* __restrict__ rp, const float* __restrict__ invl,
                   float* __restrict__ out)
{
  int bm = blockIdx.x;                     // 0..4095
  int tid = threadIdx.x;
  size_t off = (size_t)bm*D_ + tid*4;
  f32x4 v = *(const f32x4*)&rp[off];
  #pragma unroll
  for (int s = 1; s < 4; ++s)
    v += *(const f32x4*)&rp[(size_t)s*B_*M_*D_ + off];
  float sc = invl[bm];
  v *= sc;
  *(f32x4*)&out[off] = v;
}

// ---------------- fallback (tiny ws): correct, slow fp32 ----------------
__global__ void fallback_kernel(const float* __restrict__ qs,
                                const float* __restrict__ mem,
                                float* __restrict__ out)
{
  __shared__ float w_lds[4][4096];
  __shared__ float mem_s[4][1024];
  __shared__ float redb[256];
  int blk = blockIdx.x;
  int b = blk >> 7;
  int m0 = (blk & 127)*4;
  int tid = threadIdx.x;

  for (int i = tid; i < 4*1024; i += 256)
    mem_s[i>>10][i&1023] = mem[(size_t)(m0 + (i>>10))*D_ + (i&1023)];
  __syncthreads();

  float mx[4] = {-3e38f,-3e38f,-3e38f,-3e38f};
  for (int l = tid; l < L_; l += 256) {
    const float* qp = qs + ((size_t)b*L_ + l)*D_;
    float dot[4] = {0,0,0,0};
    for (int dd = 0; dd < D_; dd += 4) {
      f32x4 qv = *(const f32x4*)(qp + dd);
      #pragma unroll
      for (int mi=0; mi<4; ++mi)
        dot[mi] += qv[0]*mem_s[mi][dd] + qv[1]*mem_s[mi][dd+1]
                 + qv[2]*mem_s[mi][dd+2] + qv[3]*mem_s[mi][dd+3];
    }
    #pragma unroll
    for (int mi=0; mi<4; ++mi) { w_lds[mi][l] = dot[mi]; mx[mi] = fmaxf(mx[mi], dot[mi]); }
  }
  float Mv[4], Zv[4];
  for (int mi=0; mi<4; ++mi) {
    redb[tid] = mx[mi]; __syncthreads();
    for (int s=128; s>0; s>>=1) { if (tid<s) redb[tid]=fmaxf(redb[tid],redb[tid+s]); __syncthreads(); }
    Mv[mi] = redb[0]; __syncthreads();
  }
  float sm[4] = {0,0,0,0};
  for (int l = tid; l < L_; l += 256)
    #pragma unroll
    for (int mi=0; mi<4; ++mi) {
      float wv = __expf(w_lds[mi][l] - Mv[mi]);
      w_lds[mi][l] = wv; sm[mi] += wv;
    }
  for (int mi=0; mi<4; ++mi) {
    redb[tid] = sm[mi]; __syncthreads();
    for (int s=128; s>0; s>>=1) { if (tid<s) redb[tid]+=redb[tid+s]; __syncthreads(); }
    Zv[mi] = redb[0]; __syncthreads();
  }
  int d0 = tid*4;
  f32x4 a[4];
  #pragma unroll
  for (int mi=0;mi<4;++mi) a[mi] = (f32x4){0,0,0,0};
  for (int l = 0; l < L_; ++l) {
    f32x4 qv = *(const f32x4*)(qs + ((size_t)b*L_ + l)*D_ + d0);
    #pragma unroll
    for (int mi=0; mi<4; ++mi) a[mi] += qv * w_lds[mi][l];
  }
  #pragma unroll
  for (int mi=0; mi<4; ++mi) {
    float invz = 1.f/Zv[mi];
    #pragma unroll
    for (int c=0; c<4; ++c)
      out[((size_t)b*M_ + m0 + mi)*D_ + d0 + c] = a[mi][c]*invz;
  }
}

extern "C" void kernel_launch(void* const* d_in, const int* in_sizes, int n_in,
                              void* d_out, int out_size, void* d_ws, size_t ws_size,
                              hipStream_t stream) {
  const float* qs  = (const float*)d_in[0];
  const float* mem = (const float*)d_in[1];
  float* out = (float*)d_out;

  // tuple output: r [8*512*1024] then memory [512*1024]
  hipMemcpyAsync(out + (size_t)B_*M_*D_, mem, (size_t)M_*D_*sizeof(float),
                 hipMemcpyDeviceToDevice, stream);

  if (ws_size >= (size_t)WS_NEED) {
    char* base = (char*)d_ws;
    halfT* mem16 = (halfT*)(base + OFF_MEM16);
    halfT* qs16  = (halfT*)(base + OFF_QS16);
    float* S     = (float*)(base + OFF_S);
    halfT* P16   = (halfT*)(base + OFF_P16);
    float* invl  = (float*)(base + OFF_INVL);
    float* rp    = (float*)(base + OFF_RP);    // overlays S (dead after softmax)

    prep_mem16<<<256, 256, 0, stream>>>(mem, mem16);
    prep_qs16<<<2048, 256, 0, stream>>>(qs, qs16);
    gemm_qk<<<256, 512, 0, stream>>>(mem16, qs16, S);
    softmax_rows<<<4096, 256, 0, stream>>>(S, P16, invl);
    gemm_pv<<<256, 512, 0, stream>>>(P16, qs16, rp);
    combine_scale<<<4096, 256, 0, stream>>>(rp, invl, out);
  } else {
    fallback_kernel<<<1024, 256, 0, stream>>>(qs, mem, out);
  }
}